// Round 3
// baseline (147.706 us; speedup 1.0000x reference)
//
#include <hip/hip_runtime.h>

// MultiHeadSelfAttention: B=8 N=1024 E=768 H=12 D=64
// Pipeline: cvt(x) / transpose-cvt(Wqkv,Wfc)
//           -> GEMM1 (8-phase-style bf16 mfma, epilogue -> qh/kh/vh, Q pre-scaled)
//           -> trv (vh -> vt [b,h,d,n])
//           -> flash attention (K/V LDS-staged dbuf + XOR swizzle, swapped QK^T)
//           -> GEMM2 (same template, f32 out + bias)
// GEMM template: BM=256 BN=128 BK=64, 8 waves (4M x 2N), 3-slot LDS ring (144KB),
// counted vmcnt(6) (one K-tile always in flight), chunk^row&7 LDS swizzle,
// 2 phases/K-tile {ds_read, stage, bar, lgkm0, 16 MFMA, bar}, setprio around MFMA.
// ws usage: 80,216,064 bytes.

typedef unsigned short u16;
typedef unsigned int u32;
typedef __attribute__((ext_vector_type(8))) short short8;  // 8 x bf16 (4 VGPR)
typedef __attribute__((ext_vector_type(4))) float f32x4;

#define DEV static __device__ __forceinline__

DEV u16 f2bf(float f) {  // round-to-nearest-even f32 -> bf16 bits
  union { float f; u32 u; } v; v.f = f;
  return (u16)((v.u + 0x7FFFu + ((v.u >> 16) & 1u)) >> 16);
}

DEV void gload_lds16(const void* g, void* l) {
  // LDS dest is wave-uniform base; HW writes lane i at base + i*16B.
  __builtin_amdgcn_global_load_lds(
      (const __attribute__((address_space(1))) void*)g,
      (__attribute__((address_space(3))) void*)l, 16, 0, 0);
}

// ---------------- f32 -> bf16 elementwise (8 elems/thread) ----------------
__global__ void cvt_bf16_kernel(const float* __restrict__ in, u16* __restrict__ out, int n8) {
  int idx = blockIdx.x * blockDim.x + threadIdx.x;
  int stride = gridDim.x * blockDim.x;
  for (int i = idx; i < n8; i += stride) {
    float4 a = reinterpret_cast<const float4*>(in)[2 * i];
    float4 b = reinterpret_cast<const float4*>(in)[2 * i + 1];
    uint4 o;
    o.x = f2bf(a.x) | ((u32)f2bf(a.y) << 16);
    o.y = f2bf(a.z) | ((u32)f2bf(a.w) << 16);
    o.z = f2bf(b.x) | ((u32)f2bf(b.y) << 16);
    o.w = f2bf(b.z) | ((u32)f2bf(b.w) << 16);
    reinterpret_cast<uint4*>(out)[i] = o;
  }
}

// ------------- W [K][Nn] f32 -> Wt [Nn][K] bf16, 64x64 LDS tiles -------------
__global__ void trcvt_kernel(const float* __restrict__ in, u16* __restrict__ out,
                             int K, int Nn) {
  __shared__ u16 tile[64][72];
  int ntiles = Nn >> 6;
  int tk = blockIdx.x / ntiles, tn = blockIdx.x % ntiles;
  int k0 = tk << 6, n0 = tn << 6;
  int t = threadIdx.x;
  int r = t >> 4;            // 0..15
  int c4 = (t & 15) << 2;    // 0,4,..,60
#pragma unroll
  for (int ps = 0; ps < 4; ++ps) {
    int k = r + ps * 16;
    float4 v = *reinterpret_cast<const float4*>(&in[(size_t)(k0 + k) * Nn + n0 + c4]);
    tile[c4 + 0][k] = f2bf(v.x);
    tile[c4 + 1][k] = f2bf(v.y);
    tile[c4 + 2][k] = f2bf(v.z);
    tile[c4 + 3][k] = f2bf(v.w);
  }
  __syncthreads();
  int nr = t >> 3;           // 0..31
  int c8 = (t & 7) << 3;     // 0..56
#pragma unroll
  for (int ps = 0; ps < 2; ++ps) {
    int n = nr + ps * 32;
    uint4 v = *reinterpret_cast<const uint4*>(&tile[n][c8]);
    *reinterpret_cast<uint4*>(&out[(size_t)(n0 + n) * K + k0 + c8]) = v;
  }
}

// ------- vh [bh][n][64] -> vt [bh][64][n] (64-n tiles per (b,h)) -------
__global__ void trv_kernel(const u16* __restrict__ vh, u16* __restrict__ vt) {
  __shared__ u16 tile[64][72];
  int nt = blockIdx.x & 15;    // n tile 0..15
  int bh = blockIdx.x >> 4;    // 0..95
  int n0 = nt << 6;
  int t = threadIdx.x;
  int nr = t >> 3;             // 0..31
  int d8 = (t & 7) << 3;
  const u16* src = vh + ((size_t)bh * 1024 + n0) * 64;
#pragma unroll
  for (int ps = 0; ps < 2; ++ps) {
    int n = nr + ps * 32;
    uint4 v = *reinterpret_cast<const uint4*>(&src[(size_t)n * 64 + d8]);
    const u16* e = reinterpret_cast<const u16*>(&v);
#pragma unroll
    for (int j = 0; j < 8; ++j) tile[d8 + j][n] = e[j];
  }
  __syncthreads();
  u16* dst = vt + ((size_t)bh * 64) * 1024 + n0;
#pragma unroll
  for (int ps = 0; ps < 2; ++ps) {
    int d = nr + ps * 32;
    uint4 v = *reinterpret_cast<const uint4*>(&tile[d][d8]);
    *reinterpret_cast<uint4*>(&dst[(size_t)d * 1024 + d8]) = v;
  }
}

// ---------------- phase-pipelined bf16 GEMM, K fixed = 768 ----------------
// C[M][Nn] = A[M][768] * Bt[Nn][768]^T (+bias)
// MODE 0: f32 flat out.  MODE 2: split epilogue to qh/kh/vh [b,h,n,d], Q scaled.
template <int MODE>
__global__ __launch_bounds__(512, 2) void gemm8p(
    const u16* __restrict__ A, const u16* __restrict__ Bt,
    const float* __restrict__ bias, void* __restrict__ Cout,
    u16* __restrict__ qh, u16* __restrict__ kh, u16* __restrict__ vh,
    int Nn) {
  __shared__ u16 As[3][256 * 64];   // 96 KB: 3-slot ring, A K-tiles
  __shared__ u16 Bs[3][128 * 64];   // 48 KB: 3-slot ring, B K-tiles
  const int nTn = Nn >> 7;
  const int nwg = gridDim.x;
  int wg = blockIdx.x;
  wg = (wg & 7) * (nwg >> 3) + (wg >> 3);   // XCD swizzle (nwg % 8 == 0)
  const int tm = wg / nTn, tn = wg % nTn;
  const int m0 = tm << 8, n0 = tn << 7;
  const int tid = threadIdx.x;
  const int w = tid >> 6, lane = tid & 63;
  const int g = lane >> 4, p = lane & 15;
  const int wr = w & 3, wc = w >> 2;        // wave -> 64x64 out at (wr*64, wc*64)

  // staging: each gload covers 64 rows (8 rows/wave, lane>>3 in-wave row).
  // LDS holds (row, c) = global chunk c^(row&7); dest linear -> pre-swizzle src.
  const int srow = lane >> 3;               // 0..7
  const int schunk = (lane & 7) ^ srow;     // source chunk for this lane
  const u16* Asrc = A + (size_t)(m0 + w * 8 + srow) * 768 + schunk * 8;
  const u16* Bsrc = Bt + (size_t)(n0 + w * 8 + srow) * 768 + schunk * 8;
  // frag-read swizzled chunk byte offsets (u16 units) for k-half 0 / 1
  const int c0 = ((0 + g) ^ (p & 7)) << 3;
  const int c1 = ((4 + g) ^ (p & 7)) << 3;

  f32x4 acc[4][4] = {};

#define STAGE_A(k, j, s) \
  gload_lds16(Asrc + (size_t)(j) * 64 * 768 + (k) * 64, &As[s][((j) * 64 + w * 8) * 64])
#define STAGE_B(k, j, s) \
  gload_lds16(Bsrc + (size_t)(j) * 64 * 768 + (k) * 64, &Bs[s][((j) * 64 + w * 8) * 64])

  // prologue: stage K-tiles 0 and 1 (6 gloads each)
  STAGE_A(0, 0, 0); STAGE_A(0, 1, 0); STAGE_B(0, 0, 0);
  STAGE_A(0, 2, 0); STAGE_A(0, 3, 0); STAGE_B(0, 1, 0);
  STAGE_A(1, 0, 1); STAGE_A(1, 1, 1); STAGE_B(1, 0, 1);
  STAGE_A(1, 2, 1); STAGE_A(1, 3, 1); STAGE_B(1, 1, 1);
  asm volatile("s_waitcnt vmcnt(6)");       // K-tile 0 landed (tile 1 in flight)
  __builtin_amdgcn_sched_barrier(0);
  __builtin_amdgcn_s_barrier();

#pragma unroll
  for (int k = 0; k < 12; ++k) {
    const int s = k % 3;
    const int sn = (k + 2) % 3;
    const u16* as = As[s];
    const u16* bs = Bs[s];
    short8 bfr[4][2], afr[2][2];
    // ---------- phase A: read B all + A half0; stage 3; MFMA quadrant 0 ----------
#pragma unroll
    for (int nb = 0; nb < 4; ++nb) {
      const u16* rb = bs + (wc * 64 + nb * 16 + p) * 64;
      bfr[nb][0] = *reinterpret_cast<const short8*>(rb + c0);
      bfr[nb][1] = *reinterpret_cast<const short8*>(rb + c1);
    }
#pragma unroll
    for (int mb = 0; mb < 2; ++mb) {
      const u16* ra = as + (wr * 64 + mb * 16 + p) * 64;
      afr[mb][0] = *reinterpret_cast<const short8*>(ra + c0);
      afr[mb][1] = *reinterpret_cast<const short8*>(ra + c1);
    }
    if (k < 10) { STAGE_A(k + 2, 0, sn); STAGE_A(k + 2, 1, sn); STAGE_B(k + 2, 0, sn); }
    __builtin_amdgcn_s_barrier();
    asm volatile("s_waitcnt lgkmcnt(0)");
    __builtin_amdgcn_sched_barrier(0);
    __builtin_amdgcn_s_setprio(1);
#pragma unroll
    for (int mb = 0; mb < 2; ++mb)
#pragma unroll
      for (int nb = 0; nb < 4; ++nb) {
        acc[mb][nb] = __builtin_amdgcn_mfma_f32_16x16x32_bf16(afr[mb][0], bfr[nb][0], acc[mb][nb], 0, 0, 0);
        acc[mb][nb] = __builtin_amdgcn_mfma_f32_16x16x32_bf16(afr[mb][1], bfr[nb][1], acc[mb][nb], 0, 0, 0);
      }
    __builtin_amdgcn_s_setprio(0);
    __builtin_amdgcn_s_barrier();
    // ---------- phase B: read A half1; stage 3; MFMA quadrant 1 ----------
#pragma unroll
    for (int mb = 0; mb < 2; ++mb) {
      const u16* ra = as + (wr * 64 + (mb + 2) * 16 + p) * 64;
      afr[mb][0] = *reinterpret_cast<const short8*>(ra + c0);
      afr[mb][1] = *reinterpret_cast<const short8*>(ra + c1);
    }
    if (k < 10) { STAGE_A(k + 2, 2, sn); STAGE_A(k + 2, 3, sn); STAGE_B(k + 2, 1, sn); }
    __builtin_amdgcn_s_barrier();
    asm volatile("s_waitcnt lgkmcnt(0)");
    __builtin_amdgcn_sched_barrier(0);
    __builtin_amdgcn_s_setprio(1);
#pragma unroll
    for (int mb = 0; mb < 2; ++mb)
#pragma unroll
      for (int nb = 0; nb < 4; ++nb) {
        acc[mb + 2][nb] = __builtin_amdgcn_mfma_f32_16x16x32_bf16(afr[mb][0], bfr[nb][0], acc[mb + 2][nb], 0, 0, 0);
        acc[mb + 2][nb] = __builtin_amdgcn_mfma_f32_16x16x32_bf16(afr[mb][1], bfr[nb][1], acc[mb + 2][nb], 0, 0, 0);
      }
    __builtin_amdgcn_s_setprio(0);
    // end-of-K-tile: ensure next tile landed before its reads (counted, not 0)
    if (k < 10) asm volatile("s_waitcnt vmcnt(6)");
    else if (k == 10) asm volatile("s_waitcnt vmcnt(0)");
    __builtin_amdgcn_sched_barrier(0);
    __builtin_amdgcn_s_barrier();
  }
#undef STAGE_A
#undef STAGE_B

  const float qscale = 0.036084391824351615f;  // 1/sqrt(768)
#pragma unroll
  for (int nb = 0; nb < 4; ++nb) {
    int ncol = n0 + wc * 64 + nb * 16 + p;
    float bv = bias[ncol];
    if (MODE == 0) {
#pragma unroll
      for (int mb = 0; mb < 4; ++mb)
#pragma unroll
        for (int r = 0; r < 4; ++r) {
          int m = m0 + wr * 64 + mb * 16 + g * 4 + r;  // C/D: row=(lane>>4)*4+reg
          ((float*)Cout)[(size_t)m * Nn + ncol] = acc[mb][nb][r] + bv;
        }
    } else {
      int h64 = ncol >> 6;                 // 0..35
      int which = h64 / 12;                // 0=q 1=k 2=v
      int hh = h64 - which * 12;
      int d = nb * 16 + p;                 // ncol & 63 (nb*16 folds into h64 when >=64? no: d = ncol&63)
      d = ncol & 63;
      u16* dst = which == 0 ? qh : (which == 1 ? kh : vh);
      float sc = which == 0 ? qscale : 1.f;
#pragma unroll
      for (int mb = 0; mb < 4; ++mb)
#pragma unroll
        for (int r = 0; r < 4; ++r) {
          int m = m0 + wr * 64 + mb * 16 + g * 4 + r;
          int bb = m >> 10, nr = m & 1023;
          dst[(((size_t)bb * 12 + hh) * 1024 + nr) * 64 + d] = f2bf((acc[mb][nb][r] + bv) * sc);
        }
    }
  }
}

// ---------------- flash attention (unchanged from R2) ----------------
// grid: bh(96) * 8 q-tiles of 128 rows; 512 thr / 8 waves, wave owns 16 q-rows.
__global__ __launch_bounds__(512, 6) void attn_kernel(
    const u16* __restrict__ qh, const u16* __restrict__ kh,
    const u16* __restrict__ vt, u16* __restrict__ ao) {
  __shared__ u16 Ks[2][64 * 64];
  __shared__ u16 Vs[2][64 * 64];
  __shared__ u16 Ps[8][16 * 64];
  const int bid = blockIdx.x;
  const int qt = bid & 7;
  const int bh = bid >> 3;
  const int b = bh / 12, h = bh % 12;
  const int tid = threadIdx.x;
  const int w = tid >> 6, lane = tid & 63;
  const int g = lane >> 4, p = lane & 15;
  const int qrow = qt * 128 + w * 16;

  const u16* qbase = qh + ((size_t)bh * 1024 + qrow + p) * 64;
  short8 qf0 = *reinterpret_cast<const short8*>(qbase + g * 8);
  short8 qf1 = *reinterpret_cast<const short8*>(qbase + 32 + g * 8);

  const int ci = w * 64 + lane;              // 0..511
  const int crow = ci >> 3;                  // 0..63
  const int csw = (ci & 7) ^ (crow & 7);     // swizzled source chunk
  const u16* ksrc = kh + (((size_t)bh * 1024 + crow) << 6) + csw * 8;
  const u16* vsrc = vt + ((size_t)bh * 64 + crow) * 1024 + csw * 8;
  u16* myp = Ps[w];

  const int sw = p & 7;
  const int c0 = (g ^ sw) << 3;
  const int c1 = ((4 + g) ^ sw) << 3;

  float m_run = -1e30f, l_run = 0.f;
  f32x4 oacc[4] = {};

  gload_lds16(ksrc, &Ks[0][w * 512]);
  gload_lds16(vsrc, &Vs[0][w * 512]);
  __syncthreads();

  int buf = 0;
  for (int kt = 0; kt < 1024; kt += 64) {
    if (kt < 960) {
      gload_lds16(ksrc + ((kt + 64) << 6), &Ks[buf ^ 1][w * 512]);
      gload_lds16(vsrc + (kt + 64), &Vs[buf ^ 1][w * 512]);
    }

    f32x4 s[4];
    __builtin_amdgcn_s_setprio(1);
#pragma unroll
    for (int jb = 0; jb < 4; ++jb) {
      const u16* kb = &Ks[buf][(jb * 16 + p) * 64];
      short8 k0 = *reinterpret_cast<const short8*>(kb + c0);
      short8 k1 = *reinterpret_cast<const short8*>(kb + c1);
      f32x4 z = {};
      z = __builtin_amdgcn_mfma_f32_16x16x32_bf16(k0, qf0, z, 0, 0, 0);
      z = __builtin_amdgcn_mfma_f32_16x16x32_bf16(k1, qf1, z, 0, 0, 0);
      s[jb] = z;
    }
    __builtin_amdgcn_s_setprio(0);

    float tmax = -1e30f;
#pragma unroll
    for (int jb = 0; jb < 4; ++jb)
#pragma unroll
      for (int r = 0; r < 4; ++r) tmax = fmaxf(tmax, s[jb][r]);
    tmax = fmaxf(tmax, __shfl_xor(tmax, 16));
    tmax = fmaxf(tmax, __shfl_xor(tmax, 32));
    float m_new = fmaxf(m_run, tmax);
    float alpha = __expf(m_run - m_new);
    float lsum = 0.f;
#pragma unroll
    for (int jb = 0; jb < 4; ++jb)
#pragma unroll
      for (int r = 0; r < 4; ++r) {
        float e = __expf(s[jb][r] - m_new);
        s[jb][r] = e;
        lsum += e;
      }
    lsum += __shfl_xor(lsum, 16);
    lsum += __shfl_xor(lsum, 32);
    l_run = l_run * alpha + lsum;
    m_run = m_new;

#pragma unroll
    for (int jb = 0; jb < 4; ++jb) {
      uint2 pk;
      pk.x = f2bf(s[jb][0]) | ((u32)f2bf(s[jb][1]) << 16);
      pk.y = f2bf(s[jb][2]) | ((u32)f2bf(s[jb][3]) << 16);
      int c = 2 * jb + (g >> 1);
      *reinterpret_cast<uint2*>(&myp[p * 64 + ((c ^ sw) << 3) + ((g & 1) << 2)]) = pk;
    }

    float al[4];
#pragma unroll
    for (int r = 0; r < 4; ++r) al[r] = __shfl(alpha, g * 4 + r);
#pragma unroll
    for (int nb = 0; nb < 4; ++nb)
#pragma unroll
      for (int r = 0; r < 4; ++r) oacc[nb][r] *= al[r];

    short8 pa0 = *reinterpret_cast<const short8*>(&myp[p * 64 + c0]);
    short8 pa1 = *reinterpret_cast<const short8*>(&myp[p * 64 + c1]);
    __builtin_amdgcn_s_setprio(1);
#pragma unroll
    for (int nb = 0; nb < 4; ++nb) {
      const u16* vb = &Vs[buf][(nb * 16 + p) * 64];
      short8 v0 = *reinterpret_cast<const short8*>(vb + c0);
      short8 v1 = *reinterpret_cast<const short8*>(vb + c1);
      oacc[nb] = __builtin_amdgcn_mfma_f32_16x16x32_bf16(pa0, v0, oacc[nb], 0, 0, 0);
      oacc[nb] = __builtin_amdgcn_mfma_f32_16x16x32_bf16(pa1, v1, oacc[nb], 0, 0, 0);
    }
    __builtin_amdgcn_s_setprio(0);

    __syncthreads();
    buf ^= 1;
  }

  float li[4];
#pragma unroll
  for (int r = 0; r < 4; ++r) li[r] = 1.f / __shfl(l_run, g * 4 + r);
  u16* obase = ao + ((size_t)(b * 1024 + qrow)) * 768 + h * 64;
#pragma unroll
  for (int nb = 0; nb < 4; ++nb)
#pragma unroll
    for (int r = 0; r < 4; ++r)
      obase[(size_t)(g * 4 + r) * 768 + nb * 16 + p] = f2bf(oacc[nb][r] * li[r]);
}

// ---------------- launch ----------------
extern "C" void kernel_launch(void* const* d_in, const int* in_sizes, int n_in,
                              void* d_out, int out_size, void* d_ws, size_t ws_size,
                              hipStream_t stream) {
  const float* x = (const float*)d_in[0];      // [8,1024,768]
  const float* Wqkv = (const float*)d_in[1];   // [768,2304]
  const float* bqkv = (const float*)d_in[2];   // [2304]
  const float* Wfc = (const float*)d_in[3];    // [768,768]
  const float* bfc = (const float*)d_in[4];    // [768]
  float* out = (float*)d_out;                  // [8,1024,768] f32

  char* ws = (char*)d_ws;
  u16* xb    = (u16*)(ws);                 // 12,582,912 B : x bf16 [8192][768]
  u16* wqkvT = (u16*)(ws + 12582912);      //  3,538,944 B : [2304][768]
  u16* wfcT  = (u16*)(ws + 16121856);      //  1,179,648 B : [768][768]
  u16* qh    = (u16*)(ws + 17301504);      // 12,582,912 B : [96][1024][64] (scaled)
  u16* kh    = (u16*)(ws + 29884416);      // 12,582,912 B : [96][1024][64]
  u16* vh    = (u16*)(ws + 42467328);      // 12,582,912 B : [96][1024][64]
  u16* vt    = (u16*)(ws + 55050240);      // 12,582,912 B : [96][64][1024]
  u16* ao    = (u16*)(ws + 67633152);      // 12,582,912 B : [8192][768]

  cvt_bf16_kernel<<<2048, 256, 0, stream>>>(x, xb, (8192 * 768) / 8);
  trcvt_kernel<<<12 * 36, 256, 0, stream>>>(Wqkv, wqkvT, 768, 2304);
  trcvt_kernel<<<12 * 12, 256, 0, stream>>>(Wfc, wfcT, 768, 768);
  gemm8p<2><<<576, 512, 0, stream>>>(xb, wqkvT, bqkv, nullptr, qh, kh, vh, 2304);
  trv_kernel<<<96 * 16, 256, 0, stream>>>(vh, vt);
  attn_kernel<<<96 * 8, 512, 0, stream>>>(qh, kh, vt, ao);
  gemm8p<0><<<192, 512, 0, stream>>>(ao, wfcT, bfc, out, nullptr, nullptr, nullptr, 768);
}

// Round 4
// 138.736 us; speedup vs baseline: 1.0646x; 1.0646x over previous
//
#include <hip/hip_runtime.h>

// MultiHeadSelfAttention: B=8 N=1024 E=768 H=12 D=64
// Pipeline: cvt(x) / transpose-cvt(Wqkv,Wfc)
//           -> GEMM1 (fine-phase bf16 mfma, epilogue -> qh/kh/vh, Q pre-scaled)
//           -> trv (vh -> vt [b,h,d,n])
//           -> flash attention (K/V LDS-staged dbuf + XOR swizzle, swapped QK^T)
//           -> GEMM2 (same template, f32 out + bias)
// GEMM template: BM=256 BN=128 BK=32, 8 waves (4M x 2N), 3-slot LDS ring (72KB
// -> 2 blocks/CU), 1 phase per K-tile {8 ds_read_b128, 3 gload, bar, lgkm0,
// 16 MFMA, counted vmcnt(3), bar}, chunk^(row&3) swizzle, setprio around MFMA.
// ws usage: 80,216,064 bytes.

typedef unsigned short u16;
typedef unsigned int u32;
typedef __attribute__((ext_vector_type(8))) short short8;  // 8 x bf16 (4 VGPR)
typedef __attribute__((ext_vector_type(4))) float f32x4;

#define DEV static __device__ __forceinline__

DEV u16 f2bf(float f) {  // round-to-nearest-even f32 -> bf16 bits
  union { float f; u32 u; } v; v.f = f;
  return (u16)((v.u + 0x7FFFu + ((v.u >> 16) & 1u)) >> 16);
}

DEV void gload_lds16(const void* g, void* l) {
  // LDS dest is wave-uniform base; HW writes lane i at base + i*16B.
  __builtin_amdgcn_global_load_lds(
      (const __attribute__((address_space(1))) void*)g,
      (__attribute__((address_space(3))) void*)l, 16, 0, 0);
}

// ---------------- f32 -> bf16 elementwise (8 elems/thread) ----------------
__global__ void cvt_bf16_kernel(const float* __restrict__ in, u16* __restrict__ out, int n8) {
  int idx = blockIdx.x * blockDim.x + threadIdx.x;
  int stride = gridDim.x * blockDim.x;
  for (int i = idx; i < n8; i += stride) {
    float4 a = reinterpret_cast<const float4*>(in)[2 * i];
    float4 b = reinterpret_cast<const float4*>(in)[2 * i + 1];
    uint4 o;
    o.x = f2bf(a.x) | ((u32)f2bf(a.y) << 16);
    o.y = f2bf(a.z) | ((u32)f2bf(a.w) << 16);
    o.z = f2bf(b.x) | ((u32)f2bf(b.y) << 16);
    o.w = f2bf(b.z) | ((u32)f2bf(b.w) << 16);
    reinterpret_cast<uint4*>(out)[i] = o;
  }
}

// ------------- W [K][Nn] f32 -> Wt [Nn][K] bf16, 64x64 LDS tiles -------------
__global__ void trcvt_kernel(const float* __restrict__ in, u16* __restrict__ out,
                             int K, int Nn) {
  __shared__ u16 tile[64][72];
  int ntiles = Nn >> 6;
  int tk = blockIdx.x / ntiles, tn = blockIdx.x % ntiles;
  int k0 = tk << 6, n0 = tn << 6;
  int t = threadIdx.x;
  int r = t >> 4;            // 0..15
  int c4 = (t & 15) << 2;    // 0,4,..,60
#pragma unroll
  for (int ps = 0; ps < 4; ++ps) {
    int k = r + ps * 16;
    float4 v = *reinterpret_cast<const float4*>(&in[(size_t)(k0 + k) * Nn + n0 + c4]);
    tile[c4 + 0][k] = f2bf(v.x);
    tile[c4 + 1][k] = f2bf(v.y);
    tile[c4 + 2][k] = f2bf(v.z);
    tile[c4 + 3][k] = f2bf(v.w);
  }
  __syncthreads();
  int nr = t >> 3;           // 0..31
  int c8 = (t & 7) << 3;     // 0..56
#pragma unroll
  for (int ps = 0; ps < 2; ++ps) {
    int n = nr + ps * 32;
    uint4 v = *reinterpret_cast<const uint4*>(&tile[n][c8]);
    *reinterpret_cast<uint4*>(&out[(size_t)(n0 + n) * K + k0 + c8]) = v;
  }
}

// ------- vh [bh][n][64] -> vt [bh][64][n] (64-n tiles per (b,h)) -------
__global__ void trv_kernel(const u16* __restrict__ vh, u16* __restrict__ vt) {
  __shared__ u16 tile[64][72];
  int nt = blockIdx.x & 15;    // n tile 0..15
  int bh = blockIdx.x >> 4;    // 0..95
  int n0 = nt << 6;
  int t = threadIdx.x;
  int nr = t >> 3;             // 0..31
  int d8 = (t & 7) << 3;
  const u16* src = vh + ((size_t)bh * 1024 + n0) * 64;
#pragma unroll
  for (int ps = 0; ps < 2; ++ps) {
    int n = nr + ps * 32;
    uint4 v = *reinterpret_cast<const uint4*>(&src[(size_t)n * 64 + d8]);
    const u16* e = reinterpret_cast<const u16*>(&v);
#pragma unroll
    for (int j = 0; j < 8; ++j) tile[d8 + j][n] = e[j];
  }
  __syncthreads();
  u16* dst = vt + ((size_t)bh * 64) * 1024 + n0;
#pragma unroll
  for (int ps = 0; ps < 2; ++ps) {
    int d = nr + ps * 32;
    uint4 v = *reinterpret_cast<const uint4*>(&tile[d][d8]);
    *reinterpret_cast<uint4*>(&dst[(size_t)d * 1024 + d8]) = v;
  }
}

// ---------------- fine-phase bf16 GEMM, K fixed = 768 ----------------
// C[M][Nn] = A[M][768] * Bt[Nn][768]^T (+bias)
// MODE 0: f32 flat out.  MODE 2: split epilogue to qh/kh/vh [b,h,n,d], Q scaled.
template <int MODE>
__global__ __launch_bounds__(512, 4) void gemm_fp(
    const u16* __restrict__ A, const u16* __restrict__ Bt,
    const float* __restrict__ bias, void* __restrict__ Cout,
    u16* __restrict__ qh, u16* __restrict__ kh, u16* __restrict__ vh,
    int Nn) {
  __shared__ u16 As[3][256 * 32];   // 48 KB: 3-slot ring, A K-tiles
  __shared__ u16 Bs[3][128 * 32];   // 24 KB: 3-slot ring, B K-tiles
  const int nTn = Nn >> 7;
  const int nwg = gridDim.x;
  int wg = blockIdx.x;
  wg = (wg & 7) * (nwg >> 3) + (wg >> 3);   // XCD swizzle (nwg % 8 == 0)
  const int tm = wg / nTn, tn = wg % nTn;
  const int m0 = tm << 8, n0 = tn << 7;
  const int tid = threadIdx.x;
  const int w = tid >> 6, lane = tid & 63;
  const int g = lane >> 4, p = lane & 15;
  const int wr = w & 3, wc = w >> 2;        // wave -> 64x64 out at (wr*64, wc*64)

  // staging: gload = 16 rows x 32 elems (row = 64B = 4 chunks of 8 elems).
  // LDS holds (row, c) = global chunk c^(row&3); dest linear -> pre-swizzle src.
  const int srow = lane >> 2;               // 0..15
  const int schunk = (lane & 3) ^ (srow & 3);
  const u16* Asrc = A + (size_t)(m0 + w * 32 + srow) * 768 + schunk * 8;
  const u16* Bsrc = Bt + (size_t)(n0 + w * 16 + srow) * 768 + schunk * 8;
  // frag read: chunk g of row(..+p) lives at LDS chunk g^(p&3)
  const int csw = (g ^ (p & 3)) << 3;       // u16 offset within row

  f32x4 acc[4][4] = {};

#define STAGE(kt, s)                                                        \
  do {                                                                      \
    gload_lds16(Asrc + (size_t)(kt) * 32, &As[s][(w * 32) * 32]);           \
    gload_lds16(Asrc + (size_t)(kt) * 32 + 16 * 768, &As[s][(w * 32 + 16) * 32]); \
    gload_lds16(Bsrc + (size_t)(kt) * 32, &Bs[s][(w * 16) * 32]);           \
  } while (0)

  // prologue: stage tiles 0,1,2 into slots 0,1,2 (9 gloads/wave outstanding)
  STAGE(0, 0);
  STAGE(1, 1);
  STAGE(2, 2);
  asm volatile("s_waitcnt vmcnt(6)" ::: "memory");  // tile 0 landed
  __builtin_amdgcn_sched_barrier(0);
  __builtin_amdgcn_s_barrier();

  int s = 0;
  for (int k = 0; k < 24; ++k) {
    const u16* as = As[s];
    const u16* bs = Bs[s];
    // ---- phase: 8 ds_read_b128 (this tile's frags) ----
    short8 af[4], bf[4];
#pragma unroll
    for (int mb = 0; mb < 4; ++mb)
      af[mb] = *reinterpret_cast<const short8*>(&as[(wr * 64 + mb * 16 + p) * 32 + csw]);
#pragma unroll
    for (int nb = 0; nb < 4; ++nb)
      bf[nb] = *reinterpret_cast<const short8*>(&bs[(wc * 64 + nb * 16 + p) * 32 + csw]);
    // ---- stage tile k+2 into the slot freed after tile k-1 ----
    if (k < 22) {
      int sn = s + 2; if (sn >= 3) sn -= 3;
      STAGE(k + 2, sn);
    }
    __builtin_amdgcn_s_barrier();
    asm volatile("s_waitcnt lgkmcnt(0)" ::: "memory");
    __builtin_amdgcn_sched_barrier(0);
    __builtin_amdgcn_s_setprio(1);
#pragma unroll
    for (int mb = 0; mb < 4; ++mb)
#pragma unroll
      for (int nb = 0; nb < 4; ++nb)
        acc[mb][nb] = __builtin_amdgcn_mfma_f32_16x16x32_bf16(af[mb], bf[nb], acc[mb][nb], 0, 0, 0);
    __builtin_amdgcn_s_setprio(0);
    // counted wait: tile k+1 landed (tile k+2's 3 loads stay in flight)
    if (k < 22) asm volatile("s_waitcnt vmcnt(3)" ::: "memory");
    else if (k == 22) asm volatile("s_waitcnt vmcnt(0)" ::: "memory");
    __builtin_amdgcn_sched_barrier(0);
    __builtin_amdgcn_s_barrier();
    ++s; if (s >= 3) s = 0;
  }
#undef STAGE

  const float qscale = 0.036084391824351615f;  // 1/sqrt(768)
#pragma unroll
  for (int nb = 0; nb < 4; ++nb) {
    int ncol = n0 + wc * 64 + nb * 16 + p;
    float bv = bias[ncol];
    if (MODE == 0) {
#pragma unroll
      for (int mb = 0; mb < 4; ++mb)
#pragma unroll
        for (int r = 0; r < 4; ++r) {
          int m = m0 + wr * 64 + mb * 16 + g * 4 + r;  // C/D: row=(lane>>4)*4+reg
          ((float*)Cout)[(size_t)m * Nn + ncol] = acc[mb][nb][r] + bv;
        }
    } else {
      int h64 = ncol >> 6;                 // 0..35
      int which = h64 / 12;                // 0=q 1=k 2=v
      int hh = h64 - which * 12;
      int d = ncol & 63;
      u16* dst = which == 0 ? qh : (which == 1 ? kh : vh);
      float sc = which == 0 ? qscale : 1.f;
#pragma unroll
      for (int mb = 0; mb < 4; ++mb)
#pragma unroll
        for (int r = 0; r < 4; ++r) {
          int m = m0 + wr * 64 + mb * 16 + g * 4 + r;
          int bb = m >> 10, nr = m & 1023;
          dst[(((size_t)bb * 12 + hh) * 1024 + nr) * 64 + d] = f2bf((acc[mb][nb][r] + bv) * sc);
        }
    }
  }
}

// ---------------- flash attention (unchanged from R2) ----------------
// grid: bh(96) * 8 q-tiles of 128 rows; 512 thr / 8 waves, wave owns 16 q-rows.
__global__ __launch_bounds__(512, 6) void attn_kernel(
    const u16* __restrict__ qh, const u16* __restrict__ kh,
    const u16* __restrict__ vt, u16* __restrict__ ao) {
  __shared__ u16 Ks[2][64 * 64];
  __shared__ u16 Vs[2][64 * 64];
  __shared__ u16 Ps[8][16 * 64];
  const int bid = blockIdx.x;
  const int qt = bid & 7;
  const int bh = bid >> 3;
  const int b = bh / 12, h = bh % 12;
  const int tid = threadIdx.x;
  const int w = tid >> 6, lane = tid & 63;
  const int g = lane >> 4, p = lane & 15;
  const int qrow = qt * 128 + w * 16;

  const u16* qbase = qh + ((size_t)bh * 1024 + qrow + p) * 64;
  short8 qf0 = *reinterpret_cast<const short8*>(qbase + g * 8);
  short8 qf1 = *reinterpret_cast<const short8*>(qbase + 32 + g * 8);

  const int ci = w * 64 + lane;              // 0..511
  const int crow = ci >> 3;                  // 0..63
  const int csw = (ci & 7) ^ (crow & 7);     // swizzled source chunk
  const u16* ksrc = kh + (((size_t)bh * 1024 + crow) << 6) + csw * 8;
  const u16* vsrc = vt + ((size_t)bh * 64 + crow) * 1024 + csw * 8;
  u16* myp = Ps[w];

  const int sw = p & 7;
  const int c0 = (g ^ sw) << 3;
  const int c1 = ((4 + g) ^ sw) << 3;

  float m_run = -1e30f, l_run = 0.f;
  f32x4 oacc[4] = {};

  gload_lds16(ksrc, &Ks[0][w * 512]);
  gload_lds16(vsrc, &Vs[0][w * 512]);
  __syncthreads();

  int buf = 0;
  for (int kt = 0; kt < 1024; kt += 64) {
    if (kt < 960) {
      gload_lds16(ksrc + ((kt + 64) << 6), &Ks[buf ^ 1][w * 512]);
      gload_lds16(vsrc + (kt + 64), &Vs[buf ^ 1][w * 512]);
    }

    f32x4 s[4];
    __builtin_amdgcn_s_setprio(1);
#pragma unroll
    for (int jb = 0; jb < 4; ++jb) {
      const u16* kb = &Ks[buf][(jb * 16 + p) * 64];
      short8 k0 = *reinterpret_cast<const short8*>(kb + c0);
      short8 k1 = *reinterpret_cast<const short8*>(kb + c1);
      f32x4 z = {};
      z = __builtin_amdgcn_mfma_f32_16x16x32_bf16(k0, qf0, z, 0, 0, 0);
      z = __builtin_amdgcn_mfma_f32_16x16x32_bf16(k1, qf1, z, 0, 0, 0);
      s[jb] = z;
    }
    __builtin_amdgcn_s_setprio(0);

    float tmax = -1e30f;
#pragma unroll
    for (int jb = 0; jb < 4; ++jb)
#pragma unroll
      for (int r = 0; r < 4; ++r) tmax = fmaxf(tmax, s[jb][r]);
    tmax = fmaxf(tmax, __shfl_xor(tmax, 16));
    tmax = fmaxf(tmax, __shfl_xor(tmax, 32));
    float m_new = fmaxf(m_run, tmax);
    float alpha = __expf(m_run - m_new);
    float lsum = 0.f;
#pragma unroll
    for (int jb = 0; jb < 4; ++jb)
#pragma unroll
      for (int r = 0; r < 4; ++r) {
        float e = __expf(s[jb][r] - m_new);
        s[jb][r] = e;
        lsum += e;
      }
    lsum += __shfl_xor(lsum, 16);
    lsum += __shfl_xor(lsum, 32);
    l_run = l_run * alpha + lsum;
    m_run = m_new;

#pragma unroll
    for (int jb = 0; jb < 4; ++jb) {
      uint2 pk;
      pk.x = f2bf(s[jb][0]) | ((u32)f2bf(s[jb][1]) << 16);
      pk.y = f2bf(s[jb][2]) | ((u32)f2bf(s[jb][3]) << 16);
      int c = 2 * jb + (g >> 1);
      *reinterpret_cast<uint2*>(&myp[p * 64 + ((c ^ sw) << 3) + ((g & 1) << 2)]) = pk;
    }

    float al[4];
#pragma unroll
    for (int r = 0; r < 4; ++r) al[r] = __shfl(alpha, g * 4 + r);
#pragma unroll
    for (int nb = 0; nb < 4; ++nb)
#pragma unroll
      for (int r = 0; r < 4; ++r) oacc[nb][r] *= al[r];

    short8 pa0 = *reinterpret_cast<const short8*>(&myp[p * 64 + c0]);
    short8 pa1 = *reinterpret_cast<const short8*>(&myp[p * 64 + c1]);
    __builtin_amdgcn_s_setprio(1);
#pragma unroll
    for (int nb = 0; nb < 4; ++nb) {
      const u16* vb = &Vs[buf][(nb * 16 + p) * 64];
      short8 v0 = *reinterpret_cast<const short8*>(vb + c0);
      short8 v1 = *reinterpret_cast<const short8*>(vb + c1);
      oacc[nb] = __builtin_amdgcn_mfma_f32_16x16x32_bf16(pa0, v0, oacc[nb], 0, 0, 0);
      oacc[nb] = __builtin_amdgcn_mfma_f32_16x16x32_bf16(pa1, v1, oacc[nb], 0, 0, 0);
    }
    __builtin_amdgcn_s_setprio(0);

    __syncthreads();
    buf ^= 1;
  }

  float li[4];
#pragma unroll
  for (int r = 0; r < 4; ++r) li[r] = 1.f / __shfl(l_run, g * 4 + r);
  u16* obase = ao + ((size_t)(b * 1024 + qrow)) * 768 + h * 64;
#pragma unroll
  for (int nb = 0; nb < 4; ++nb)
#pragma unroll
    for (int r = 0; r < 4; ++r)
      obase[(size_t)(g * 4 + r) * 768 + nb * 16 + p] = f2bf(oacc[nb][r] * li[r]);
}

// ---------------- launch ----------------
extern "C" void kernel_launch(void* const* d_in, const int* in_sizes, int n_in,
                              void* d_out, int out_size, void* d_ws, size_t ws_size,
                              hipStream_t stream) {
  const float* x = (const float*)d_in[0];      // [8,1024,768]
  const float* Wqkv = (const float*)d_in[1];   // [768,2304]
  const float* bqkv = (const float*)d_in[2];   // [2304]
  const float* Wfc = (const float*)d_in[3];    // [768,768]
  const float* bfc = (const float*)d_in[4];    // [768]
  float* out = (float*)d_out;                  // [8,1024,768] f32

  char* ws = (char*)d_ws;
  u16* xb    = (u16*)(ws);                 // 12,582,912 B : x bf16 [8192][768]
  u16* wqkvT = (u16*)(ws + 12582912);      //  3,538,944 B : [2304][768]
  u16* wfcT  = (u16*)(ws + 16121856);      //  1,179,648 B : [768][768]
  u16* qh    = (u16*)(ws + 17301504);      // 12,582,912 B : [96][1024][64] (scaled)
  u16* kh    = (u16*)(ws + 29884416);      // 12,582,912 B : [96][1024][64]
  u16* vh    = (u16*)(ws + 42467328);      // 12,582,912 B : [96][1024][64]
  u16* vt    = (u16*)(ws + 55050240);      // 12,582,912 B : [96][64][1024]
  u16* ao    = (u16*)(ws + 67633152);      // 12,582,912 B : [8192][768]

  cvt_bf16_kernel<<<2048, 256, 0, stream>>>(x, xb, (8192 * 768) / 8);
  trcvt_kernel<<<12 * 36, 256, 0, stream>>>(Wqkv, wqkvT, 768, 2304);
  trcvt_kernel<<<12 * 12, 256, 0, stream>>>(Wfc, wfcT, 768, 768);
  gemm_fp<2><<<576, 512, 0, stream>>>(xb, wqkvT, bqkv, nullptr, qh, kh, vh, 2304);
  trv_kernel<<<96 * 16, 256, 0, stream>>>(vh, vt);
  attn_kernel<<<96 * 8, 512, 0, stream>>>(qh, kh, vt, ao);
  gemm_fp<0><<<192, 512, 0, stream>>>(ao, wfcT, bfc, out, nullptr, nullptr, nullptr, 768);
}